// Round 9
// baseline (227.772 us; speedup 1.0000x reference)
//
#include <hip/hip_runtime.h>

// Attention block: x[2,2048,1024] fp32, w_qkv[3072,1024], w_out[1024,1024], b_out[1024]
// bf16 MFMA GEMMs + flash attention.
// Round 9: key-range split (blockIdx.z, no-max softmax combines linearly) ->
// grid 2048 = 8 blocks/CU, 8 independent barrier domains. V fragments in
// register double-buffer from global (L2-resident; unroll-2 forces liveness).
// LDS 12288 B (K dbuf + P). Partials: bf16 numerator + fp32 denom in dead ws
// regions; combine kernel divides and emits ob.

typedef __attribute__((ext_vector_type(4))) float f32x4;
typedef __attribute__((ext_vector_type(8))) __bf16 bf16x8;
typedef unsigned short u16;

#define DEV static __device__ __forceinline__

DEV u16 f2bf(float x) {  // RNE float->bf16 (epilogues only)
  union { float f; unsigned u; } c; c.f = x;
  unsigned r = c.u + 0x7FFFu + ((c.u >> 16) & 1u);
  return (u16)(r >> 16);
}

DEV float bf2f(unsigned lo16) {  // bf16 (in low 16 bits) -> float
  union { unsigned u; float f; } c; c.u = lo16 << 16; return c.f;
}

DEV void gld16(const void* g, void* l) {  // async global->LDS, 16B/lane
  __builtin_amdgcn_global_load_lds((__attribute__((address_space(1))) void*)g,
                                   (__attribute__((address_space(3))) void*)l, 16, 0, 0);
}

// Fused fp32->bf16 convert for all three tensors (one dispatch).
__global__ __launch_bounds__(256) void cvt_all_kernel(const float* __restrict__ x,
                                                      const float* __restrict__ wq,
                                                      const float* __restrict__ wo,
                                                      u16* __restrict__ xo,
                                                      u16* __restrict__ wqo,
                                                      u16* __restrict__ woo) {
  int t = blockIdx.x * 256 + threadIdx.x;
  const float* in; u16* out; int i;
  if (t < 1048576)       { in = x;  out = xo;  i = t; }
  else if (t < 1835008)  { in = wq; out = wqo; i = t - 1048576; }
  else                   { in = wo; out = woo; i = t - 1835008; }
  float4 v = ((const float4*)in)[i];
  uint2 o;
  o.x = (unsigned)f2bf(v.x) | ((unsigned)f2bf(v.y) << 16);
  o.y = (unsigned)f2bf(v.z) | ((unsigned)f2bf(v.w) << 16);
  ((uint2*)out)[i] = o;
}

// C = A[M,K] * B[N,K]^T, 128x128 tile, BK=32, 4 waves of 64x64, bf16 MFMA.
// Epilogue: scatter to q/k/v buffers [B=2,H=16,L=2048,Dh=64] bf16.
// Q is pre-scaled by scale*log2(e) so flash can exp2 the raw MFMA output.
__global__ __launch_bounds__(256) void gemm_qkv_kernel(const u16* __restrict__ A,
                                                       const u16* __restrict__ Bw,
                                                       u16* __restrict__ qb,
                                                       u16* __restrict__ kb,
                                                       u16* __restrict__ vb) {
  __shared__ alignas(16) u16 As[128 * 32];
  __shared__ alignas(16) u16 Bs[128 * 32];
  const int K = 1024;
  int tid = threadIdx.x, wave = tid >> 6, lane = tid & 63, quad = lane >> 4, l15 = lane & 15;
  int m0 = blockIdx.y * 128, n0 = blockIdx.x * 128;
  f32x4 z = {0.f, 0.f, 0.f, 0.f};
  f32x4 acc[4][4];
  for (int i = 0; i < 4; i++) for (int j = 0; j < 4; j++) acc[i][j] = z;
  int r0 = tid >> 2, ko = (tid & 3) * 8;
  const u16* ga0 = A + (m0 + r0) * K + ko;
  const u16* ga1 = A + (m0 + r0 + 64) * K + ko;
  const u16* gb0 = Bw + (n0 + r0) * K + ko;
  const u16* gb1 = Bw + (n0 + r0 + 64) * K + ko;
  u16 *la0 = &As[tid * 8], *la1 = &As[(256 + tid) * 8];
  u16 *lb0 = &Bs[tid * 8], *lb1 = &Bs[(256 + tid) * 8];
  int ar = (wave & 1) * 64, bc = (wave >> 1) * 64;
  for (int k0 = 0; k0 < K; k0 += 32) {
    gld16(ga0 + k0, la0); gld16(ga1 + k0, la1);
    gld16(gb0 + k0, lb0); gld16(gb1 + k0, lb1);
    __syncthreads();
    bf16x8 af[4], bfr[4];
    for (int i = 0; i < 4; i++) af[i]  = *(const bf16x8*)&As[(ar + i * 16 + l15) * 32 + quad * 8];
    for (int j = 0; j < 4; j++) bfr[j] = *(const bf16x8*)&Bs[(bc + j * 16 + l15) * 32 + quad * 8];
    for (int i = 0; i < 4; i++)
      for (int j = 0; j < 4; j++)
        acc[i][j] = __builtin_amdgcn_mfma_f32_16x16x32_bf16(af[i], bfr[j], acc[i][j], 0, 0, 0);
    __syncthreads();
  }
  int which = n0 >> 10;  // block-uniform: 0=q 1=k 2=v
  u16* dst = which == 0 ? qb : (which == 1 ? kb : vb);
  float qs = which == 0 ? 0.045112882054311f : 1.0f;  // (1/32)*log2(e)
  for (int i = 0; i < 4; i++)
    for (int j = 0; j < 4; j++) {
      int o = n0 + bc + j * 16 + l15;
      int h = (o & 1023) >> 6, d = o & 63;
      for (int r = 0; r < 4; r++) {
        int m = m0 + ar + i * 16 + quad * 4 + r;
        int b = m >> 11, l = m & 2047;
        dst[((b * 16 + h) * 2048 + l) * 64 + d] = f2bf(acc[i][j][r] * qs);
      }
    }
}

// v[bh][l][d] -> vt[bh][d][l]
__global__ __launch_bounds__(256) void transpose_v_kernel(const u16* __restrict__ vb,
                                                          u16* __restrict__ vtb) {
  __shared__ alignas(16) u16 T[64 * 72];
  int lt = blockIdx.x, bh = blockIdx.y;
  int t = threadIdx.x;
  for (int ld = 0; ld < 2; ld++) {
    int idx = ld * 256 + t;
    int l = idx >> 3, d0 = (idx & 7) * 8;
    uint4 v = *(const uint4*)(vb + (bh * 2048 + lt * 64 + l) * 64 + d0);
    *(uint4*)&T[l * 72 + d0] = v;
  }
  __syncthreads();
  for (int ld = 0; ld < 2; ld++) {
    int idx = ld * 256 + t;
    int d = idx >> 3, l0 = (idx & 7) * 8;
    union { u16 us[8]; uint4 v; } tmp;
    for (int i2 = 0; i2 < 8; i2++) tmp.us[i2] = T[(l0 + i2) * 72 + d];
    *(uint4*)(vtb + (bh * 64 + d) * 2048 + lt * 64 + l0) = tmp.v;
  }
}

// Flash attention v6: 128 threads = 2 waves x 32 q-rows, 64-row q-tile,
// 32-key tiles x 32 iterations, keys split by blockIdx.z (1024 keys each).
// K: LDS dbuf DMA (stride-64 rows, blk^(row&7) swizzle). V: register dbuf
// from global (lane-only frags, L2-resident). P: 64x32 stride-32 swizzled.
// Emits bf16 partial numerators + fp32 partial denominators (no division).
__global__ __launch_bounds__(128, 4) void flash_kernel(const u16* __restrict__ qb,
                                                       const u16* __restrict__ kb,
                                                       const u16* __restrict__ vtb,
                                                       u16* __restrict__ pO0,
                                                       u16* __restrict__ pO1,
                                                       float* __restrict__ dn) {
  __shared__ alignas(16) u16 Ks[2][32 * 64];
  __shared__ alignas(16) u16 Ps[64 * 32];
  int qt = blockIdx.x, bh = blockIdx.y, ph = blockIdx.z;
  int b = bh >> 4, h = bh & 15;
  int tid = threadIdx.x, wave = tid >> 6, lane = tid & 63, quad = lane >> 4, l15 = lane & 15;
  int q0 = qt * 64;
  int kbase = ph * 1024;  // this block's key range: kbase .. kbase+1023
  u16* pO = ph ? pO1 : pO0;
  const u16* qg = qb + (bh * 2048 + q0) * 64;
  const u16* kgb = kb + (bh * 2048 + kbase) * 64;
  const u16* vgb = vtb + bh * 64 * 2048 + kbase;

  // Q fragments: direct global->VGPR, once (16B contiguous rows of qb)
  bf16x8 aq[2][2];
  for (int i = 0; i < 2; i++)
    for (int kk = 0; kk < 2; kk++)
      aq[i][kk] = *(const bf16x8*)(qg + (wave * 32 + i * 16 + l15) * 64 + kk * 32 + quad * 8);

  // stage K tile 0 (4 KB; 128 thr x 2 iters x 16 B)
  for (int it = 0; it < 2; it++) {
    int idx = it * 128 + tid;
    int kr = idx >> 3, kblk = (idx & 7) ^ (kr & 7);
    gld16(kgb + kr * 64 + kblk * 8, &Ks[0][idx * 8]);
  }
  // V fragments tile 0: register buffer (row = j*16+l15 of vt, keys quad*8..+7)
  bf16x8 bv[2][4];
  for (int j = 0; j < 4; j++)
    bv[0][j] = *(const bf16x8*)(vgb + (j * 16 + l15) * 2048 + quad * 8);
  __syncthreads();

  bf16x8 vone;
  for (int e = 0; e < 8; e++) vone[e] = (__bf16)1.0f;
  f32x4 z = {0.f, 0.f, 0.f, 0.f};
  f32x4 o_[2][4], o4[2];
  for (int i = 0; i < 2; i++) { for (int j = 0; j < 4; j++) o_[i][j] = z; o4[i] = z; }

  // P write bases (swizzle from r8, verified): 4 lane bases + immediates
  int b0 = l15 >> 3, q1 = quad & 1, e7 = l15 & 7;
  int wrow = (wave * 32 + quad * 4) * 32 + e7;
  u16* pwb[2][2];
  for (int r1 = 0; r1 < 2; r1++)
    for (int j = 0; j < 2; j++)
      pwb[r1][j] = &Ps[wrow + 8 * ((b0 ^ r1) + 2 * (j ^ q1))];
  const u16* pra = &Ps[(wave * 32 + l15) * 32 + 8 * (quad ^ ((l15 >> 1) & 3))];
  int kro = l15 * 64;
  int kbA = 8 * ((quad) ^ (l15 & 7));
  int kbB = 8 * ((4 + quad) ^ (l15 & 7));

#pragma unroll 2
  for (int kt = 0; kt < 32; kt++) {
    int cur = kt & 1;
    if (kt < 31) {  // prefetch next K tile (DMA) + next V frags (registers)
      int nxt = cur ^ 1;
      for (int it = 0; it < 2; it++) {
        int idx = it * 128 + tid;
        int kr = idx >> 3, kblk = (idx & 7) ^ (kr & 7);
        gld16(kgb + ((kt + 1) * 32 + kr) * 64 + kblk * 8, &Ks[nxt][idx * 8]);
      }
      for (int j = 0; j < 4; j++)
        bv[nxt][j] = *(const bf16x8*)(vgb + (j * 16 + l15) * 2048 + (kt + 1) * 32 + quad * 8);
    }
    const u16* ks = Ks[cur];
    // K fragments: 4 b128 (j = key block 0/1, kk = k half)
    bf16x8 bk[2][2];
    for (int j = 0; j < 2; j++) {
      bk[j][0] = *(const bf16x8*)&ks[j * 1024 + kro + kbA];
      bk[j][1] = *(const bf16x8*)&ks[j * 1024 + kro + kbB];
    }
    // QK: S[i][j] (16q x 16key), K=64 in 2 MFMAs
    f32x4 s[2][2];
    for (int i = 0; i < 2; i++)
      for (int j = 0; j < 2; j++) {
        s[i][j] = __builtin_amdgcn_mfma_f32_16x16x32_bf16(aq[i][0], bk[j][0], z, 0, 0, 0);
        s[i][j] = __builtin_amdgcn_mfma_f32_16x16x32_bf16(aq[i][1], bk[j][1], s[i][j], 0, 0, 0);
      }
    // exp2 (Q pre-scaled) + round-half-up bf16 hi-store to swizzled P
    for (int i = 0; i < 2; i++)
      for (int j = 0; j < 2; j++)
        for (int r = 0; r < 4; r++) {
          float p = __builtin_amdgcn_exp2f(s[i][j][r]);
          unsigned u = __float_as_uint(p) + 0x8000u;
          pwb[r >> 1][j][(i * 16 + r) * 32] = (u16)(u >> 16);
        }
    // P fragments + PV + denominator (K=32: single MFMA per (i,j))
    for (int i = 0; i < 2; i++) {
      bf16x8 ap = *(const bf16x8*)&pra[i * 512];
      for (int j = 0; j < 4; j++)
        o_[i][j] = __builtin_amdgcn_mfma_f32_16x16x32_bf16(ap, bv[cur][j], o_[i][j], 0, 0, 0);
      o4[i] = __builtin_amdgcn_mfma_f32_16x16x32_bf16(ap, vone, o4[i], 0, 0, 0);
    }
    __syncthreads();  // drains next-K DMA; fences cur K + P reuse
  }
  // partial numerator (bf16) + partial denominator (fp32, lane l15==0 writes)
  for (int i = 0; i < 2; i++) {
    for (int j = 0; j < 4; j++) {
      int c = h * 64 + j * 16 + l15;
      for (int r = 0; r < 4; r++) {
        int q = q0 + wave * 32 + i * 16 + quad * 4 + r;
        pO[(b * 2048 + q) * 1024 + c] = f2bf(o_[i][j][r]);
      }
    }
    if (l15 == 0)
      for (int r = 0; r < 4; r++) {
        int q = q0 + wave * 32 + i * 16 + quad * 4 + r;
        dn[ph * 65536 + bh * 2048 + q] = o4[i][r];
      }
  }
}

// ob = (pO0 + pO1) / (dn0 + dn1), bf16 out. 4 elems/thread.
__global__ __launch_bounds__(256) void combine_kernel(const u16* __restrict__ pO0,
                                                      const u16* __restrict__ pO1,
                                                      const float* __restrict__ dn,
                                                      u16* __restrict__ ob) {
  int t = blockIdx.x * 256 + threadIdx.x;  // t < 1048576
  int e = t * 4;
  int b = e >> 21, c = e & 1023, l = (e >> 10) & 2047;
  int li = ((b << 4) + (c >> 6)) * 2048 + l;
  float inv = 1.0f / (dn[li] + dn[65536 + li]);
  uint2 u1 = ((const uint2*)pO0)[t];
  uint2 u2 = ((const uint2*)pO1)[t];
  float f0 = (bf2f(u1.x & 0xffff) + bf2f(u2.x & 0xffff)) * inv;
  float f1 = (bf2f(u1.x >> 16)    + bf2f(u2.x >> 16))    * inv;
  float f2 = (bf2f(u1.y & 0xffff) + bf2f(u2.y & 0xffff)) * inv;
  float f3 = (bf2f(u1.y >> 16)    + bf2f(u2.y >> 16))    * inv;
  uint2 o;
  o.x = (unsigned)f2bf(f0) | ((unsigned)f2bf(f1) << 16);
  o.y = (unsigned)f2bf(f2) | ((unsigned)f2bf(f3) << 16);
  ((uint2*)ob)[t] = o;
}

// out[M,N] = A[M,K] * B[N,K]^T + bias[N], fp32 out. 128x64 tile -> grid 512 (2/CU).
__global__ __launch_bounds__(256) void gemm_out_kernel(const u16* __restrict__ A,
                                                       const u16* __restrict__ Bw,
                                                       const float* __restrict__ bias,
                                                       float* __restrict__ out) {
  __shared__ alignas(16) u16 As[128 * 32];
  __shared__ alignas(16) u16 Bs[64 * 32];
  const int K = 1024;
  int tid = threadIdx.x, wave = tid >> 6, lane = tid & 63, quad = lane >> 4, l15 = lane & 15;
  int m0 = blockIdx.y * 128, n0 = blockIdx.x * 64;
  f32x4 z = {0.f, 0.f, 0.f, 0.f};
  f32x4 acc[4][2];
  for (int i = 0; i < 4; i++) for (int j = 0; j < 2; j++) acc[i][j] = z;
  int r0 = tid >> 2, ko = (tid & 3) * 8;
  const u16* ga0 = A + (m0 + r0) * K + ko;
  const u16* ga1 = A + (m0 + r0 + 64) * K + ko;
  const u16* gb0 = Bw + (n0 + r0) * K + ko;
  u16 *la0 = &As[tid * 8], *la1 = &As[(256 + tid) * 8];
  u16 *lb0 = &Bs[tid * 8];
  int ar = (wave & 1) * 64, bc = (wave >> 1) * 32;
  for (int k0 = 0; k0 < K; k0 += 32) {
    gld16(ga0 + k0, la0); gld16(ga1 + k0, la1);
    if (r0 < 64) gld16(gb0 + k0, lb0);
    __syncthreads();
    bf16x8 af[4], bfr[2];
    for (int i = 0; i < 4; i++) af[i]  = *(const bf16x8*)&As[(ar + i * 16 + l15) * 32 + quad * 8];
    for (int j = 0; j < 2; j++) bfr[j] = *(const bf16x8*)&Bs[(bc + j * 16 + l15) * 32 + quad * 8];
    for (int i = 0; i < 4; i++)
      for (int j = 0; j < 2; j++)
        acc[i][j] = __builtin_amdgcn_mfma_f32_16x16x32_bf16(af[i], bfr[j], acc[i][j], 0, 0, 0);
    __syncthreads();
  }
  for (int i = 0; i < 4; i++)
    for (int j = 0; j < 2; j++) {
      int o = n0 + bc + j * 16 + l15;
      float bo = bias[o];
      for (int r = 0; r < 4; r++) {
        int m = m0 + ar + i * 16 + quad * 4 + r;
        out[m * 1024 + o] = acc[i][j][r] + bo;
      }
    }
}

extern "C" void kernel_launch(void* const* d_in, const int* in_sizes, int n_in,
                              void* d_out, int out_size, void* d_ws, size_t ws_size,
                              hipStream_t stream) {
  const float* x     = (const float*)d_in[0];
  const float* w_qkv = (const float*)d_in[1];
  const float* w_out = (const float*)d_in[2];
  const float* b_out = (const float*)d_in[3];
  float* out = (float*)d_out;
  u16* ws = (u16*)d_ws;
  u16* x_bf    = ws;             // 4194304  (dead after gemm_qkv -> reused as pO0)
  u16* wqkv_bf = ws + 4194304;   // 3145728  (dead after gemm_qkv -> reused as dn)
  u16* wout_bf = ws + 7340032;   // 1048576  (live until gemm_out)
  u16* qb      = ws + 8388608;   // 4194304  [B,H,L,64] (pre-scaled)
  u16* kb      = ws + 12582912;  // 4194304  [B,H,L,64]
  u16* vb      = ws + 16777216;  // 4194304  (dead after transpose_v -> reused as pO1)
  u16* vtb     = ws + 20971520;  // 4194304  [B,H,64,L]
  u16* ob      = ws + 25165824;  // 4194304  [B,L,C]
  u16* pO0     = x_bf;           // partial numerator, key half 0 (bf16)
  u16* pO1     = vb;             // partial numerator, key half 1 (bf16)
  float* dnb   = (float*)wqkv_bf; // partial denominators [2][32][2048] fp32

  cvt_all_kernel<<<8192, 256, 0, stream>>>(x, w_qkv, w_out, x_bf, wqkv_bf, wout_bf);
  gemm_qkv_kernel<<<dim3(24, 32), 256, 0, stream>>>(x_bf, wqkv_bf, qb, kb, vb);
  transpose_v_kernel<<<dim3(32, 32), 256, 0, stream>>>(vb, vtb);
  flash_kernel<<<dim3(32, 32, 2), 128, 0, stream>>>(qb, kb, vtb, pO0, pO1, dnb);
  combine_kernel<<<4096, 256, 0, stream>>>(pO0, pO1, dnb, ob);
  gemm_out_kernel<<<dim3(16, 32), 256, 0, stream>>>(ob, wout_bf, b_out, out);
}

// Round 10
// 198.605 us; speedup vs baseline: 1.1469x; 1.1469x over previous
//
#include <hip/hip_runtime.h>

// Attention block: x[2,2048,1024] fp32, w_qkv[3072,1024], w_out[1024,1024], b_out[1024]
// bf16 MFMA GEMMs + flash attention.
// Round 10: r9's key-split grid (2048 blocks = 8/CU, proven resident) with V
// restored to LDS dbuf DMA (r8's verified stride-32 swizzle). r9's V register
// prefetch was drained by the per-kt barrier (vmcnt(0) waits on ALL global
// loads) — only LDS-DMA prefetch belongs in a barriered K-loop. LDS 20480 B.

typedef __attribute__((ext_vector_type(4))) float f32x4;
typedef __attribute__((ext_vector_type(8))) __bf16 bf16x8;
typedef unsigned short u16;

#define DEV static __device__ __forceinline__

DEV u16 f2bf(float x) {  // RNE float->bf16 (epilogues only)
  union { float f; unsigned u; } c; c.f = x;
  unsigned r = c.u + 0x7FFFu + ((c.u >> 16) & 1u);
  return (u16)(r >> 16);
}

DEV float bf2f(unsigned lo16) {  // bf16 (in low 16 bits) -> float
  union { unsigned u; float f; } c; c.u = lo16 << 16; return c.f;
}

DEV void gld16(const void* g, void* l) {  // async global->LDS, 16B/lane
  __builtin_amdgcn_global_load_lds((__attribute__((address_space(1))) void*)g,
                                   (__attribute__((address_space(3))) void*)l, 16, 0, 0);
}

// Fused fp32->bf16 convert for all three tensors (one dispatch).
__global__ __launch_bounds__(256) void cvt_all_kernel(const float* __restrict__ x,
                                                      const float* __restrict__ wq,
                                                      const float* __restrict__ wo,
                                                      u16* __restrict__ xo,
                                                      u16* __restrict__ wqo,
                                                      u16* __restrict__ woo) {
  int t = blockIdx.x * 256 + threadIdx.x;
  const float* in; u16* out; int i;
  if (t < 1048576)       { in = x;  out = xo;  i = t; }
  else if (t < 1835008)  { in = wq; out = wqo; i = t - 1048576; }
  else                   { in = wo; out = woo; i = t - 1835008; }
  float4 v = ((const float4*)in)[i];
  uint2 o;
  o.x = (unsigned)f2bf(v.x) | ((unsigned)f2bf(v.y) << 16);
  o.y = (unsigned)f2bf(v.z) | ((unsigned)f2bf(v.w) << 16);
  ((uint2*)out)[i] = o;
}

// C = A[M,K] * B[N,K]^T, 128x128 tile, BK=32, 4 waves of 64x64, bf16 MFMA.
// Epilogue: scatter to q/k/v buffers [B=2,H=16,L=2048,Dh=64] bf16.
// Q is pre-scaled by scale*log2(e) so flash can exp2 the raw MFMA output.
__global__ __launch_bounds__(256) void gemm_qkv_kernel(const u16* __restrict__ A,
                                                       const u16* __restrict__ Bw,
                                                       u16* __restrict__ qb,
                                                       u16* __restrict__ kb,
                                                       u16* __restrict__ vb) {
  __shared__ alignas(16) u16 As[128 * 32];
  __shared__ alignas(16) u16 Bs[128 * 32];
  const int K = 1024;
  int tid = threadIdx.x, wave = tid >> 6, lane = tid & 63, quad = lane >> 4, l15 = lane & 15;
  int m0 = blockIdx.y * 128, n0 = blockIdx.x * 128;
  f32x4 z = {0.f, 0.f, 0.f, 0.f};
  f32x4 acc[4][4];
  for (int i = 0; i < 4; i++) for (int j = 0; j < 4; j++) acc[i][j] = z;
  int r0 = tid >> 2, ko = (tid & 3) * 8;
  const u16* ga0 = A + (m0 + r0) * K + ko;
  const u16* ga1 = A + (m0 + r0 + 64) * K + ko;
  const u16* gb0 = Bw + (n0 + r0) * K + ko;
  const u16* gb1 = Bw + (n0 + r0 + 64) * K + ko;
  u16 *la0 = &As[tid * 8], *la1 = &As[(256 + tid) * 8];
  u16 *lb0 = &Bs[tid * 8], *lb1 = &Bs[(256 + tid) * 8];
  int ar = (wave & 1) * 64, bc = (wave >> 1) * 64;
  for (int k0 = 0; k0 < K; k0 += 32) {
    gld16(ga0 + k0, la0); gld16(ga1 + k0, la1);
    gld16(gb0 + k0, lb0); gld16(gb1 + k0, lb1);
    __syncthreads();
    bf16x8 af[4], bfr[4];
    for (int i = 0; i < 4; i++) af[i]  = *(const bf16x8*)&As[(ar + i * 16 + l15) * 32 + quad * 8];
    for (int j = 0; j < 4; j++) bfr[j] = *(const bf16x8*)&Bs[(bc + j * 16 + l15) * 32 + quad * 8];
    for (int i = 0; i < 4; i++)
      for (int j = 0; j < 4; j++)
        acc[i][j] = __builtin_amdgcn_mfma_f32_16x16x32_bf16(af[i], bfr[j], acc[i][j], 0, 0, 0);
    __syncthreads();
  }
  int which = n0 >> 10;  // block-uniform: 0=q 1=k 2=v
  u16* dst = which == 0 ? qb : (which == 1 ? kb : vb);
  float qs = which == 0 ? 0.045112882054311f : 1.0f;  // (1/32)*log2(e)
  for (int i = 0; i < 4; i++)
    for (int j = 0; j < 4; j++) {
      int o = n0 + bc + j * 16 + l15;
      int h = (o & 1023) >> 6, d = o & 63;
      for (int r = 0; r < 4; r++) {
        int m = m0 + ar + i * 16 + quad * 4 + r;
        int b = m >> 11, l = m & 2047;
        dst[((b * 16 + h) * 2048 + l) * 64 + d] = f2bf(acc[i][j][r] * qs);
      }
    }
}

// v[bh][l][d] -> vt[bh][d][l]
__global__ __launch_bounds__(256) void transpose_v_kernel(const u16* __restrict__ vb,
                                                          u16* __restrict__ vtb) {
  __shared__ alignas(16) u16 T[64 * 72];
  int lt = blockIdx.x, bh = blockIdx.y;
  int t = threadIdx.x;
  for (int ld = 0; ld < 2; ld++) {
    int idx = ld * 256 + t;
    int l = idx >> 3, d0 = (idx & 7) * 8;
    uint4 v = *(const uint4*)(vb + (bh * 2048 + lt * 64 + l) * 64 + d0);
    *(uint4*)&T[l * 72 + d0] = v;
  }
  __syncthreads();
  for (int ld = 0; ld < 2; ld++) {
    int idx = ld * 256 + t;
    int d = idx >> 3, l0 = (idx & 7) * 8;
    union { u16 us[8]; uint4 v; } tmp;
    for (int i2 = 0; i2 < 8; i2++) tmp.us[i2] = T[(l0 + i2) * 72 + d];
    *(uint4*)(vtb + (bh * 64 + d) * 2048 + lt * 64 + l0) = tmp.v;
  }
}

// Flash attention v7: 128 threads = 2 waves x 32 q-rows, 64-row q-tile,
// 32-key tiles x 32 iterations, keys split by blockIdx.z (1024 keys each).
// K: LDS dbuf DMA (stride-64 rows, blk^(row&7)). V: LDS dbuf DMA (stride-32
// rows, blk^((row>>1)&3)). P: 64x32 stride-32 swizzled. LDS 20480 B ->
// ~7 blocks/CU with the 2048-block grid. Emits bf16 partial numerators +
// fp32 partial denominators (no-max softmax combines linearly).
__global__ __launch_bounds__(128, 4) void flash_kernel(const u16* __restrict__ qb,
                                                       const u16* __restrict__ kb,
                                                       const u16* __restrict__ vtb,
                                                       u16* __restrict__ pO0,
                                                       u16* __restrict__ pO1,
                                                       float* __restrict__ dn) {
  __shared__ alignas(16) u16 Ks[2][32 * 64];
  __shared__ alignas(16) u16 Vts[2][64 * 32];
  __shared__ alignas(16) u16 Ps[64 * 32];
  int qt = blockIdx.x, bh = blockIdx.y, ph = blockIdx.z;
  int b = bh >> 4, h = bh & 15;
  int tid = threadIdx.x, wave = tid >> 6, lane = tid & 63, quad = lane >> 4, l15 = lane & 15;
  int q0 = qt * 64;
  int kbase = ph * 1024;  // this block's key range: kbase .. kbase+1023
  u16* pO = ph ? pO1 : pO0;
  const u16* qg = qb + (bh * 2048 + q0) * 64;
  const u16* kgb = kb + (bh * 2048 + kbase) * 64;
  const u16* vgb = vtb + bh * 64 * 2048 + kbase;

  // Q fragments: direct global->VGPR, once (16B contiguous rows of qb;
  // vmcnt retires before the kt loop — not barrier-drained per iteration)
  bf16x8 aq[2][2];
  for (int i = 0; i < 2; i++)
    for (int kk = 0; kk < 2; kk++)
      aq[i][kk] = *(const bf16x8*)(qg + (wave * 32 + i * 16 + l15) * 64 + kk * 32 + quad * 8);

  // stage K/V tile 0 into buffer 0 (4 KB each; 128 thr x 2 iters x 16 B)
  for (int it = 0; it < 2; it++) {
    int idx = it * 128 + tid;
    int kr = idx >> 3, kblk = (idx & 7) ^ (kr & 7);
    gld16(kgb + kr * 64 + kblk * 8, &Ks[0][idx * 8]);
    int vr = idx >> 2, vblk = (idx & 3) ^ ((vr >> 1) & 3);
    gld16(vgb + vr * 2048 + vblk * 8, &Vts[0][idx * 8]);
  }
  __syncthreads();

  bf16x8 vone;
  for (int e = 0; e < 8; e++) vone[e] = (__bf16)1.0f;
  f32x4 z = {0.f, 0.f, 0.f, 0.f};
  f32x4 o_[2][4], o4[2];
  for (int i = 0; i < 2; i++) { for (int j = 0; j < 4; j++) o_[i][j] = z; o4[i] = z; }

  // P write bases (swizzle verified r8/r9): 4 lane bases + immediates
  int b0 = l15 >> 3, q1 = quad & 1, e7 = l15 & 7;
  int wrow = (wave * 32 + quad * 4) * 32 + e7;
  u16* pwb[2][2];
  for (int r1 = 0; r1 < 2; r1++)
    for (int j = 0; j < 2; j++)
      pwb[r1][j] = &Ps[wrow + 8 * ((b0 ^ r1) + 2 * (j ^ q1))];
  const u16* pra = &Ps[(wave * 32 + l15) * 32 + 8 * (quad ^ ((l15 >> 1) & 3))];
  int kro = l15 * 64;
  int kbA = 8 * ((quad) ^ (l15 & 7));
  int kbB = 8 * ((4 + quad) ^ (l15 & 7));
  int vro = l15 * 32 + 8 * (quad ^ ((l15 >> 1) & 3));

#pragma unroll 2
  for (int kt = 0; kt < 32; kt++) {
    int cur = kt & 1;
    if (kt < 31) {  // DMA-prefetch next K/V tile into alternate buffer
      int nxt = cur ^ 1;
      for (int it = 0; it < 2; it++) {
        int idx = it * 128 + tid;
        int kr = idx >> 3, kblk = (idx & 7) ^ (kr & 7);
        gld16(kgb + ((kt + 1) * 32 + kr) * 64 + kblk * 8, &Ks[nxt][idx * 8]);
        int vr = idx >> 2, vblk = (idx & 3) ^ ((vr >> 1) & 3);
        gld16(vgb + vr * 2048 + (kt + 1) * 32 + vblk * 8, &Vts[nxt][idx * 8]);
      }
    }
    const u16* ks = Ks[cur];
    const u16* vs = Vts[cur];
    // K fragments: 4 b128 (j = key block 0/1, kk = k half)
    bf16x8 bk[2][2];
    for (int j = 0; j < 2; j++) {
      bk[j][0] = *(const bf16x8*)&ks[j * 1024 + kro + kbA];
      bk[j][1] = *(const bf16x8*)&ks[j * 1024 + kro + kbB];
    }
    // QK: S[i][j] (16q x 16key), K=64 in 2 MFMAs
    f32x4 s[2][2];
    for (int i = 0; i < 2; i++)
      for (int j = 0; j < 2; j++) {
        s[i][j] = __builtin_amdgcn_mfma_f32_16x16x32_bf16(aq[i][0], bk[j][0], z, 0, 0, 0);
        s[i][j] = __builtin_amdgcn_mfma_f32_16x16x32_bf16(aq[i][1], bk[j][1], s[i][j], 0, 0, 0);
      }
    // exp2 (Q pre-scaled) + round-half-up bf16 hi-store to swizzled P
    for (int i = 0; i < 2; i++)
      for (int j = 0; j < 2; j++)
        for (int r = 0; r < 4; r++) {
          float p = __builtin_amdgcn_exp2f(s[i][j][r]);
          unsigned u = __float_as_uint(p) + 0x8000u;
          pwb[r >> 1][j][(i * 16 + r) * 32] = (u16)(u >> 16);
        }
    // V fragments: 4 b128 (j = d block), rows stride 32
    bf16x8 bv[4];
    for (int j = 0; j < 4; j++) bv[j] = *(const bf16x8*)&vs[j * 512 + vro];
    // P fragments + PV + denominator (K=32: single MFMA per (i,j))
    for (int i = 0; i < 2; i++) {
      bf16x8 ap = *(const bf16x8*)&pra[i * 512];
      for (int j = 0; j < 4; j++)
        o_[i][j] = __builtin_amdgcn_mfma_f32_16x16x32_bf16(ap, bv[j], o_[i][j], 0, 0, 0);
      o4[i] = __builtin_amdgcn_mfma_f32_16x16x32_bf16(ap, vone, o4[i], 0, 0, 0);
    }
    __syncthreads();  // drains next-tile DMA (only DMA is in flight); fences reuse
  }
  // partial numerator (bf16) + partial denominator (fp32, lane l15==0 writes)
  for (int i = 0; i < 2; i++) {
    for (int j = 0; j < 4; j++) {
      int c = h * 64 + j * 16 + l15;
      for (int r = 0; r < 4; r++) {
        int q = q0 + wave * 32 + i * 16 + quad * 4 + r;
        pO[(b * 2048 + q) * 1024 + c] = f2bf(o_[i][j][r]);
      }
    }
    if (l15 == 0)
      for (int r = 0; r < 4; r++) {
        int q = q0 + wave * 32 + i * 16 + quad * 4 + r;
        dn[ph * 65536 + bh * 2048 + q] = o4[i][r];
      }
  }
}

// ob = (pO0 + pO1) / (dn0 + dn1), bf16 out. 4 elems/thread.
__global__ __launch_bounds__(256) void combine_kernel(const u16* __restrict__ pO0,
                                                      const u16* __restrict__ pO1,
                                                      const float* __restrict__ dn,
                                                      u16* __restrict__ ob) {
  int t = blockIdx.x * 256 + threadIdx.x;  // t < 1048576
  int e = t * 4;
  int b = e >> 21, c = e & 1023, l = (e >> 10) & 2047;
  int li = ((b << 4) + (c >> 6)) * 2048 + l;
  float inv = 1.0f / (dn[li] + dn[65536 + li]);
  uint2 u1 = ((const uint2*)pO0)[t];
  uint2 u2 = ((const uint2*)pO1)[t];
  float f0 = (bf2f(u1.x & 0xffff) + bf2f(u2.x & 0xffff)) * inv;
  float f1 = (bf2f(u1.x >> 16)    + bf2f(u2.x >> 16))    * inv;
  float f2 = (bf2f(u1.y & 0xffff) + bf2f(u2.y & 0xffff)) * inv;
  float f3 = (bf2f(u1.y >> 16)    + bf2f(u2.y >> 16))    * inv;
  uint2 o;
  o.x = (unsigned)f2bf(f0) | ((unsigned)f2bf(f1) << 16);
  o.y = (unsigned)f2bf(f2) | ((unsigned)f2bf(f3) << 16);
  ((uint2*)ob)[t] = o;
}

// out[M,N] = A[M,K] * B[N,K]^T + bias[N], fp32 out. 128x64 tile -> grid 512 (2/CU).
__global__ __launch_bounds__(256) void gemm_out_kernel(const u16* __restrict__ A,
                                                       const u16* __restrict__ Bw,
                                                       const float* __restrict__ bias,
                                                       float* __restrict__ out) {
  __shared__ alignas(16) u16 As[128 * 32];
  __shared__ alignas(16) u16 Bs[64 * 32];
  const int K = 1024;
  int tid = threadIdx.x, wave = tid >> 6, lane = tid & 63, quad = lane >> 4, l15 = lane & 15;
  int m0 = blockIdx.y * 128, n0 = blockIdx.x * 64;
  f32x4 z = {0.f, 0.f, 0.f, 0.f};
  f32x4 acc[4][2];
  for (int i = 0; i < 4; i++) for (int j = 0; j < 2; j++) acc[i][j] = z;
  int r0 = tid >> 2, ko = (tid & 3) * 8;
  const u16* ga0 = A + (m0 + r0) * K + ko;
  const u16* ga1 = A + (m0 + r0 + 64) * K + ko;
  const u16* gb0 = Bw + (n0 + r0) * K + ko;
  u16 *la0 = &As[tid * 8], *la1 = &As[(256 + tid) * 8];
  u16 *lb0 = &Bs[tid * 8];
  int ar = (wave & 1) * 64, bc = (wave >> 1) * 32;
  for (int k0 = 0; k0 < K; k0 += 32) {
    gld16(ga0 + k0, la0); gld16(ga1 + k0, la1);
    if (r0 < 64) gld16(gb0 + k0, lb0);
    __syncthreads();
    bf16x8 af[4], bfr[2];
    for (int i = 0; i < 4; i++) af[i]  = *(const bf16x8*)&As[(ar + i * 16 + l15) * 32 + quad * 8];
    for (int j = 0; j < 2; j++) bfr[j] = *(const bf16x8*)&Bs[(bc + j * 16 + l15) * 32 + quad * 8];
    for (int i = 0; i < 4; i++)
      for (int j = 0; j < 2; j++)
        acc[i][j] = __builtin_amdgcn_mfma_f32_16x16x32_bf16(af[i], bfr[j], acc[i][j], 0, 0, 0);
    __syncthreads();
  }
  for (int i = 0; i < 4; i++)
    for (int j = 0; j < 2; j++) {
      int o = n0 + bc + j * 16 + l15;
      float bo = bias[o];
      for (int r = 0; r < 4; r++) {
        int m = m0 + ar + i * 16 + quad * 4 + r;
        out[m * 1024 + o] = acc[i][j][r] + bo;
      }
    }
}

extern "C" void kernel_launch(void* const* d_in, const int* in_sizes, int n_in,
                              void* d_out, int out_size, void* d_ws, size_t ws_size,
                              hipStream_t stream) {
  const float* x     = (const float*)d_in[0];
  const float* w_qkv = (const float*)d_in[1];
  const float* w_out = (const float*)d_in[2];
  const float* b_out = (const float*)d_in[3];
  float* out = (float*)d_out;
  u16* ws = (u16*)d_ws;
  u16* x_bf    = ws;             // 4194304  (dead after gemm_qkv -> reused as pO0)
  u16* wqkv_bf = ws + 4194304;   // 3145728  (dead after gemm_qkv -> reused as dn)
  u16* wout_bf = ws + 7340032;   // 1048576  (live until gemm_out)
  u16* qb      = ws + 8388608;   // 4194304  [B,H,L,64] (pre-scaled)
  u16* kb      = ws + 12582912;  // 4194304  [B,H,L,64]
  u16* vb      = ws + 16777216;  // 4194304  (dead after transpose_v -> reused as pO1)
  u16* vtb     = ws + 20971520;  // 4194304  [B,H,64,L]
  u16* ob      = ws + 25165824;  // 4194304  [B,L,C]
  u16* pO0     = x_bf;           // partial numerator, key half 0 (bf16)
  u16* pO1     = vb;             // partial numerator, key half 1 (bf16)
  float* dnb   = (float*)wqkv_bf; // partial denominators [2][32][2048] fp32

  cvt_all_kernel<<<8192, 256, 0, stream>>>(x, w_qkv, w_out, x_bf, wqkv_bf, wout_bf);
  gemm_qkv_kernel<<<dim3(24, 32), 256, 0, stream>>>(x_bf, wqkv_bf, qb, kb, vb);
  transpose_v_kernel<<<dim3(32, 32), 256, 0, stream>>>(vb, vtb);
  flash_kernel<<<dim3(32, 32, 2), 128, 0, stream>>>(qb, kb, vtb, pO0, pO1, dnb);
  combine_kernel<<<4096, 256, 0, stream>>>(pO0, pO1, dnb, ob);
  gemm_out_kernel<<<dim3(16, 32), 256, 0, stream>>>(ob, wout_bf, b_out, out);
}